// Round 1
// baseline (4021.171 us; speedup 1.0000x reference)
//
#include <hip/hip_runtime.h>
#include <hip/hip_bf16.h>

#define Cc 256
#define Nn 32768
#define HWc 16384
#define Bb 2

typedef float floatx4 __attribute__((ext_vector_type(4)));
typedef short bf16x8 __attribute__((ext_vector_type(8)));

__device__ __forceinline__ unsigned short f2b(float f){
    unsigned u = __float_as_uint(f);
    u += 0x7fff + ((u >> 16) & 1);
    return (unsigned short)(u >> 16);
}
__device__ __forceinline__ float b2f(unsigned short h){
    return __uint_as_float(((unsigned)h) << 16);
}

// ---------------- setup kernels ----------------
__global__ __launch_bounds__(256) void k_count(const int* __restrict__ ci,
                                               const float* __restrict__ occ,
                                               float* __restrict__ counts){
    int idx = blockIdx.x*256 + threadIdx.x;
    if (idx >= Bb*3*Nn) return;
    int n = idx & (Nn-1);
    int bg = idx >> 15;           // b*3+g
    int b = bg / 3;
    int cell = min(max(ci[idx], 0), HWc-1);
    float o = occ[(b<<15) + n];
    atomicAdd(&counts[(bg<<14) + cell], o*o);
}

__global__ __launch_bounds__(256) void k_wpt(const int* __restrict__ ci,
                                             const float* __restrict__ occ,
                                             const float* __restrict__ counts,
                                             float* __restrict__ wpt){
    int idx = blockIdx.x*256 + threadIdx.x;
    if (idx >= Bb*3*Nn) return;
    int n = idx & (Nn-1);
    int bg = idx >> 15;
    int b = bg / 3;
    int cell = min(max(ci[idx], 0), HWc-1);
    float o = occ[(b<<15) + n];
    float cnt = counts[(bg<<14) + cell];
    wpt[idx] = o / (o*cnt + 1e-6f);
}

__global__ __launch_bounds__(256) void k_wcvt(const float* __restrict__ w1,
                                              const float* __restrict__ w2,
                                              unsigned short* __restrict__ W1b,
                                              unsigned short* __restrict__ W2b){
    int idx = blockIdx.x*256 + threadIdx.x;
    if (idx >= 4*Cc*Cc) return;
    W1b[idx] = f2b(w1[idx]);
    W2b[idx] = f2b(w2[idx]);
}

// ---------------- K1: LayerNorm(smix) * wpt + atomic scatter into grid ----------------
__global__ __launch_bounds__(256) void k1_ln_scatter(const float* __restrict__ tok,
                                                     const int* __restrict__ ci,
                                                     const float* __restrict__ wpt,
                                                     const float* __restrict__ lng,
                                                     const float* __restrict__ lnb,
                                                     float* __restrict__ grid, int g){
    __shared__ float lg[Cc], lb[Cc];
    __shared__ float r1[256], r2[256];
    __shared__ float ms[128], rs[128];
    int tid = threadIdx.x;
    lg[tid] = lng[tid];
    lb[tid] = lnb[tid];
    int bi = blockIdx.x;
    int b = bi >> 8;               // 256 blocks per batch (128 points each)
    int p0 = (bi & 255) << 7;
    int sub = tid & 127;
    int half = tid >> 7;
    const float* tb = tok + ((size_t)b << 8)*Nn + p0 + sub;
    float sum = 0.f, sq = 0.f;
    for (int c = half; c < Cc; c += 2){
        float x = tb[(size_t)c << 15];
        sum += x; sq += x*x;
    }
    r1[tid] = sum; r2[tid] = sq;
    __syncthreads();
    if (tid < 128){
        float s = r1[tid] + r1[tid+128];
        float q = r2[tid] + r2[tid+128];
        float m = s * (1.f/256.f);
        float v = q * (1.f/256.f) - m*m;
        ms[tid] = m;
        rs[tid] = rsqrtf(fmaxf(v, 0.f) + 1e-5f);
    }
    __syncthreads();
    int idx = (b*3 + g)*Nn + p0 + sub;
    int cell = min(max(ci[idx], 0), HWc-1);
    float wv = wpt[idx];
    float m = ms[sub], r = rs[sub];
    float* gb = grid + ((size_t)b << 8)*HWc + cell;
    for (int c = half; c < Cc; c += 2){
        float x = tb[(size_t)c << 15];
        atomicAdd(gb + ((size_t)c << 14), ((x - m)*r*lg[c] + lb[c]) * wv);
    }
}

// ---------------- K2: fused dwconv3 -> relu -> dwconv3 (+skip) + BN partial sums ----------------
__global__ __launch_bounds__(256) void k2_conv(const float* __restrict__ grid,
                                               const float* __restrict__ skip,
                                               float* __restrict__ plane,
                                               const float* __restrict__ w1, const float* __restrict__ b1,
                                               const float* __restrict__ w2, const float* __restrict__ b2,
                                               const float* __restrict__ asc,
                                               float* __restrict__ bnS, float* __restrict__ bnQ,
                                               int useskip){
    __shared__ float it[36*132];
    __shared__ float mid[34*132];
    int tid = threadIdx.x;
    int bi = blockIdx.x;
    int rt = bi & 3;
    int bc = bi >> 2;              // b*256+c
    int c = bc & 255;
    int r0 = rt << 5;
    const float* src = grid + (size_t)bc*HWc;
    const float* sk  = skip + (size_t)bc*HWc;
    for (int i = tid; i < 36*132; i += 256){
        int r = i / 132, cc = i - r*132;
        int gy = r0 - 2 + r, gx = cc - 2;
        float v = 0.f;
        if ((unsigned)gy < 128u && (unsigned)gx < 128u){
            int o = (gy << 7) + gx;
            v = src[o];
            if (useskip) v += sk[o];
        }
        it[i] = v;
    }
    float a1[9], a2[9];
    #pragma unroll
    for (int j = 0; j < 9; ++j){ a1[j] = w1[c*9+j]; a2[j] = w2[c*9+j]; }
    float bb1 = b1[c], bb2 = b2[c], sc = asc[c];
    __syncthreads();
    for (int i = tid; i < 34*130; i += 256){
        int r = i / 130, cc = i - r*130;
        int y = r0 - 1 + r, x = cc - 1;
        float v = 0.f;
        if ((unsigned)y < 128u && (unsigned)x < 128u){
            float s = 0.f;
            #pragma unroll
            for (int j = 0; j < 9; ++j) s += a1[j] * it[(r + j/3)*132 + cc + (j%3)];
            v = fmaxf(s + bb1, 0.f);
        }
        mid[r*132 + cc] = v;
    }
    __syncthreads();
    float ps = 0.f, pq = 0.f;
    float* dst = plane + (size_t)bc*HWc;
    for (int i = tid; i < 32*128; i += 256){
        int yy = i >> 7, x = i & 127;
        float s = 0.f;
        #pragma unroll
        for (int j = 0; j < 9; ++j) s += a2[j] * mid[(yy + j/3)*132 + x + (j%3)];
        float v = s + bb2;
        dst[((r0 + yy) << 7) + x] = v;
        float t = v * sc;
        ps += t; pq += t*t;
    }
    __syncthreads();
    it[tid] = ps; it[256 + tid] = pq;
    __syncthreads();
    for (int s2 = 128; s2 > 0; s2 >>= 1){
        if (tid < s2){ it[tid] += it[tid+s2]; it[256+tid] += it[256+tid+s2]; }
        __syncthreads();
    }
    if (tid == 0){
        atomicAdd(&bnS[c], it[0]);
        atomicAdd(&bnQ[c], it[256]);
    }
}

// ---------------- K2b: fold BN into per-channel affine P,Q ----------------
__global__ __launch_bounds__(256) void k2b_bn(const float* __restrict__ bnS, const float* __restrict__ bnQ,
                                              const float* __restrict__ asc,
                                              const float* __restrict__ bng, const float* __restrict__ bnb,
                                              float* __restrict__ P, float* __restrict__ Q){
    int c = threadIdx.x;
    float mean = bnS[c] * (1.f/32768.f);
    float var  = bnQ[c] * (1.f/32768.f) - mean*mean;
    float inv  = rsqrtf(fmaxf(var, 0.f) + 1e-5f) * bng[c];
    P[c] = asc[c] * inv;
    Q[c] = bnb[c] - mean * inv;
}

// ---------------- K3t: apply sigmoid gate + transpose plane -> attp [b][hw][c] ----------------
__global__ __launch_bounds__(256) void k3t_att_t(const float* __restrict__ plane,
                                                 const float* __restrict__ P, const float* __restrict__ Q,
                                                 float* __restrict__ attp){
    __shared__ float t[32*33];
    int tid = threadIdx.x;
    int tx = tid & 31, ty = tid >> 5;
    int bi = blockIdx.x;
    int ht = bi & 511;
    int ct = (bi >> 9) & 7;
    int b  = bi >> 12;
    int c0 = ct << 5, h0 = ht << 5;
    for (int r = ty; r < 32; r += 8){
        int c = c0 + r;
        float v = plane[(((size_t)b << 8) + c)*HWc + h0 + tx];
        float s = 1.f / (1.f + __expf(-(P[c]*v + Q[c])));
        t[r*33 + tx] = s * v;
    }
    __syncthreads();
    for (int r = ty; r < 32; r += 8){
        attp[(((size_t)b << 14) + h0 + r)*Cc + c0 + tx] = t[tx*33 + r];
    }
}

// ---------------- K4: spatial-add + cmix LN + MFMA mm1(relu) + mm2 + residual ----------------
__global__ __launch_bounds__(256) void k4_cmix(const float* __restrict__ tsrc,
                                               const float* __restrict__ attp,
                                               const int* __restrict__ ci,
                                               const unsigned short* __restrict__ W1,
                                               const unsigned short* __restrict__ W2,
                                               const float* __restrict__ lng, const float* __restrict__ lnb,
                                               const float* __restrict__ b1, const float* __restrict__ b2,
                                               const float* __restrict__ csc,
                                               float* __restrict__ out, int g){
    __shared__ __align__(16) unsigned short hbuf[8448];   // h [p][c] stride 264; later h2 [c][p] stride 33
    __shared__ __align__(16) unsigned short h1buf[8448];  // h1 [p][c] stride 264
    __shared__ unsigned short rls[8448];                  // r [c][p] stride 33 (bf16)
    __shared__ float reds[256], redq[256];
    __shared__ float m_s[32], r_s[32];
    __shared__ int cell_s[32];
    __shared__ float lng_s[Cc], lnb_s[Cc], b1_s[Cc], b2s_s[Cc], cs_s[Cc];

    int tid = threadIdx.x;
    int bi = blockIdx.x;
    int b = bi >> 10;              // 1024 blocks per batch, 32 points each
    int p0 = (bi & 1023) << 5;

    lng_s[tid] = lng[tid];
    lnb_s[tid] = lnb[tid];
    b1_s[tid] = b1[tid];
    float cv = csc[tid];
    cs_s[tid] = cv;
    b2s_s[tid] = b2[tid] * cv;
    if (tid < 32){
        int cc = ci[(b*3 + g)*Nn + p0 + tid];
        cell_s[tid] = min(max(cc, 0), HWc-1);
    }
    __syncthreads();

    // stage gathered spatial contribution r[c][p] (coalesced rows of transposed attp)
    const float* ap = attp + (size_t)b * ((size_t)HWc * Cc);
    #pragma unroll 4
    for (int pp = 0; pp < 32; ++pp){
        rls[tid*33 + pp] = f2b(ap[(size_t)cell_s[pp]*Cc + tid]);
    }
    __syncthreads();

    int p = tid & 31;
    int cg = tid >> 5;             // 8 channel groups; thread covers c = cg + 8k
    float vreg[32];
    float sum = 0.f, sq = 0.f;
    const float* tb = tsrc + ((size_t)b << 8)*Nn + p0 + p;
    #pragma unroll
    for (int k = 0; k < 32; ++k){
        int c = cg + (k << 3);
        float v = tb[(size_t)c << 15] + b2f(rls[c*33 + p]);
        vreg[k] = v; sum += v; sq += v*v;
    }
    reds[tid] = sum; redq[tid] = sq;
    __syncthreads();
    if (tid < 32){
        float s = 0.f, q = 0.f;
        #pragma unroll
        for (int j = 0; j < 8; ++j){ s += reds[j*32 + tid]; q += redq[j*32 + tid]; }
        float m = s * (1.f/256.f);
        float var = q * (1.f/256.f) - m*m;
        m_s[tid] = m;
        r_s[tid] = rsqrtf(fmaxf(var, 0.f) + 1e-5f);
    }
    __syncthreads();
    float mp = m_s[p], rp = r_s[p];
    #pragma unroll
    for (int k = 0; k < 32; ++k){
        int c = cg + (k << 3);
        float hn = (vreg[k] - mp)*rp*lng_s[c] + lnb_s[c];
        hbuf[p*264 + c] = f2b(hn);
    }
    __syncthreads();

    int lane = tid & 63;
    int w = tid >> 6;
    int l15 = lane & 15;
    int q4 = lane >> 4;
    floatx4 acc[4][2];
    #pragma unroll
    for (int mi = 0; mi < 4; ++mi)
        #pragma unroll
        for (int ni = 0; ni < 2; ++ni)
            acc[mi][ni] = (floatx4){0.f, 0.f, 0.f, 0.f};

    // mm1: h1 = relu(W1 @ h + b1)
    #pragma unroll
    for (int kk = 0; kk < 8; ++kk){
        int k0 = kk*32 + q4*8;
        bf16x8 bfr[2];
        #pragma unroll
        for (int ni = 0; ni < 2; ++ni)
            bfr[ni] = *(const bf16x8*)&hbuf[(ni*16 + l15)*264 + k0];
        #pragma unroll
        for (int mi = 0; mi < 4; ++mi){
            bf16x8 af = *(const bf16x8*)&W1[(size_t)(w*64 + mi*16 + l15)*Cc + k0];
            #pragma unroll
            for (int ni = 0; ni < 2; ++ni)
                acc[mi][ni] = __builtin_amdgcn_mfma_f32_16x16x32_bf16(af, bfr[ni], acc[mi][ni], 0, 0, 0);
        }
    }
    #pragma unroll
    for (int mi = 0; mi < 4; ++mi)
        #pragma unroll
        for (int ni = 0; ni < 2; ++ni)
            #pragma unroll
            for (int r = 0; r < 4; ++r){
                int m = w*64 + mi*16 + q4*4 + r;
                int nn = ni*16 + l15;
                float v = fmaxf(acc[mi][ni][r] + b1_s[m], 0.f);
                h1buf[nn*264 + m] = f2b(v);
            }
    __syncthreads();

    // mm2: h2 = (W2 @ h1 + b2) * cmix_scale  (bias+scale folded)
    #pragma unroll
    for (int mi = 0; mi < 4; ++mi)
        #pragma unroll
        for (int ni = 0; ni < 2; ++ni)
            acc[mi][ni] = (floatx4){0.f, 0.f, 0.f, 0.f};
    #pragma unroll
    for (int kk = 0; kk < 8; ++kk){
        int k0 = kk*32 + q4*8;
        bf16x8 bfr[2];
        #pragma unroll
        for (int ni = 0; ni < 2; ++ni)
            bfr[ni] = *(const bf16x8*)&h1buf[(ni*16 + l15)*264 + k0];
        #pragma unroll
        for (int mi = 0; mi < 4; ++mi){
            bf16x8 af = *(const bf16x8*)&W2[(size_t)(w*64 + mi*16 + l15)*Cc + k0];
            #pragma unroll
            for (int ni = 0; ni < 2; ++ni)
                acc[mi][ni] = __builtin_amdgcn_mfma_f32_16x16x32_bf16(af, bfr[ni], acc[mi][ni], 0, 0, 0);
        }
    }
    #pragma unroll
    for (int mi = 0; mi < 4; ++mi)
        #pragma unroll
        for (int ni = 0; ni < 2; ++ni)
            #pragma unroll
            for (int r = 0; r < 4; ++r){
                int m = w*64 + mi*16 + q4*4 + r;
                int nn = ni*16 + l15;
                float v = acc[mi][ni][r]*cs_s[m] + b2s_s[m];
                hbuf[m*33 + nn] = f2b(v);   // reuse hbuf as h2 [c][p]
            }
    __syncthreads();

    #pragma unroll
    for (int k = 0; k < 32; ++k){
        int c = cg + (k << 3);
        out[(((size_t)b << 8) + c)*Nn + p0 + p] = vreg[k] + b2f(hbuf[c*33 + p]);
    }
}

extern "C" void kernel_launch(void* const* d_in, const int* in_sizes, int n_in,
                              void* d_out, int out_size, void* d_ws, size_t ws_size,
                              hipStream_t stream){
    (void)in_sizes; (void)n_in; (void)out_size; (void)ws_size;
    const float* tokens  = (const float*)d_in[0];
    const int*   cellind = (const int*)d_in[1];
    const float* occ     = (const float*)d_in[2];
    const float* smix_g  = (const float*)d_in[3];
    const float* smix_b  = (const float*)d_in[4];
    const float* ffn_w1  = (const float*)d_in[5];
    const float* ffn_b1  = (const float*)d_in[6];
    const float* ffn_w2  = (const float*)d_in[7];
    const float* ffn_b2  = (const float*)d_in[8];
    const float* att_sc  = (const float*)d_in[9];
    const float* bn_g    = (const float*)d_in[10];
    const float* bn_b    = (const float*)d_in[11];
    const float* cm_g    = (const float*)d_in[12];
    const float* cm_b    = (const float*)d_in[13];
    const float* cw1     = (const float*)d_in[14];
    const float* cb1     = (const float*)d_in[15];
    const float* cw2     = (const float*)d_in[16];
    const float* cb2     = (const float*)d_in[17];
    const float* cscale  = (const float*)d_in[18];
    float* out = (float*)d_out;
    char* w = (char*)d_ws;

    const size_t GRID_BYTES = (size_t)Bb*Cc*HWc*4;   // 33554432
    float* grid   = (float*)(w);
    float* planeA = (float*)(w + GRID_BYTES);
    float* planeB = (float*)(w + 2*GRID_BYTES);
    size_t o = 3*GRID_BYTES;
    float* counts = (float*)(w + o); o += (size_t)Bb*3*HWc*4;   // 393216
    float* wptb   = (float*)(w + o); o += (size_t)Bb*3*Nn*4;    // 786432
    float* bnS    = (float*)(w + o);                            // 4 x 256 floats (S,Q,P,Qaff)
    float* bnQ    = bnS + 256;
    float* Pb     = bnS + 512;
    float* Qb     = bnS + 768;
    o += 4096;
    unsigned short* W1b = (unsigned short*)(w + o);
    unsigned short* W2b = W1b + 4*Cc*Cc;

    // ---- setup (once per launch) ----
    hipMemsetAsync(counts, 0, (size_t)Bb*3*HWc*4, stream);
    k_count<<<(Bb*3*Nn)/256, 256, 0, stream>>>(cellind, occ, counts);
    k_wpt<<<(Bb*3*Nn)/256, 256, 0, stream>>>(cellind, occ, counts, wptb);
    k_wcvt<<<(4*Cc*Cc)/256, 256, 0, stream>>>(cw1, cw2, W1b, W2b);

    for (int d = 0; d < 4; ++d){
        int g = d % 3;
        int useskip = (d == 3) ? 1 : 0;
        float* plane = (d == 0) ? planeA : planeB;
        const float* tsrc = (d == 0) ? tokens : out;

        hipMemsetAsync(grid, 0, GRID_BYTES, stream);
        hipMemsetAsync(bnS, 0, 2048, stream);

        k1_ln_scatter<<<Bb*(Nn/128), 256, 0, stream>>>(tsrc, cellind, wptb,
                                                       smix_g + d*Cc, smix_b + d*Cc, grid, g);
        k2_conv<<<Bb*Cc*4, 256, 0, stream>>>(grid, planeA, plane,
                                             ffn_w1 + d*Cc*9, ffn_b1 + d*Cc,
                                             ffn_w2 + d*Cc*9, ffn_b2 + d*Cc,
                                             att_sc + d*Cc, bnS, bnQ, useskip);
        k2b_bn<<<1, 256, 0, stream>>>(bnS, bnQ, att_sc + d*Cc, bn_g + d*Cc, bn_b + d*Cc, Pb, Qb);
        // grid buffer is dead after k2_conv -> reuse it as the transposed gated plane
        k3t_att_t<<<Bb*8*512, 256, 0, stream>>>(plane, Pb, Qb, grid);
        k4_cmix<<<Bb*(Nn/32), 256, 0, stream>>>(tsrc, grid, cellind,
                                                W1b + (size_t)d*Cc*Cc, W2b + (size_t)d*Cc*Cc,
                                                cm_g + d*Cc, cm_b + d*Cc,
                                                cb1 + d*Cc, cb2 + d*Cc, cscale + d*Cc,
                                                out, g);
    }
}

// Round 2
// 1008.013 us; speedup vs baseline: 3.9892x; 3.9892x over previous
//
#include <hip/hip_runtime.h>
#include <hip/hip_bf16.h>
#include <hip/hip_fp16.h>

#define Cc 256
#define Nn 32768
#define HWc 16384
#define Bb 2

typedef float floatx4 __attribute__((ext_vector_type(4)));
typedef short bf16x8 __attribute__((ext_vector_type(8)));
typedef unsigned short ushort8v __attribute__((ext_vector_type(8)));

__device__ __forceinline__ unsigned short f2b(float f){
    unsigned u = __float_as_uint(f);
    u += 0x7fff + ((u >> 16) & 1);
    return (unsigned short)(u >> 16);
}
__device__ __forceinline__ float b2f(unsigned short h){
    return __uint_as_float(((unsigned)h) << 16);
}

// ---------------- setup kernels ----------------
__global__ __launch_bounds__(256) void k_count(const int* __restrict__ ci,
                                               const float* __restrict__ occ,
                                               float* __restrict__ fcounts,
                                               int* __restrict__ icounts){
    int idx = blockIdx.x*256 + threadIdx.x;
    if (idx >= Bb*3*Nn) return;
    int n = idx & (Nn-1);
    int bg = idx >> 15;           // b*3+g
    int b = bg / 3;
    int cell = min(max(ci[idx], 0), HWc-1);
    float o = occ[(b<<15) + n];
    atomicAdd(&fcounts[(bg<<14) + cell], o*o);
    atomicAdd(&icounts[(bg<<14) + cell], 1);
}

__global__ __launch_bounds__(256) void k_wpt(const int* __restrict__ ci,
                                             const float* __restrict__ occ,
                                             const float* __restrict__ fcounts,
                                             float* __restrict__ wpt){
    int idx = blockIdx.x*256 + threadIdx.x;
    if (idx >= Bb*3*Nn) return;
    int n = idx & (Nn-1);
    int bg = idx >> 15;
    int b = bg / 3;
    int cell = min(max(ci[idx], 0), HWc-1);
    float o = occ[(b<<15) + n];
    float cnt = fcounts[(bg<<14) + cell];
    wpt[idx] = o / (o*cnt + 1e-6f);
}

// exclusive prefix scan of per-cell int counts -> starts[HW+1], cursors copy
__global__ __launch_bounds__(256) void k_scan(const int* __restrict__ ic,
                                              int* __restrict__ starts,
                                              int* __restrict__ cursor){
    __shared__ int part[256];
    int bg = blockIdx.x;          // 0..5
    int t = threadIdx.x;
    const int* cs = ic + (bg << 14);
    int base = t * 64;
    int s = 0;
    for (int i = 0; i < 64; ++i) s += cs[base + i];
    part[t] = s;
    __syncthreads();
    for (int off = 1; off < 256; off <<= 1){
        int v = (t >= off) ? part[t - off] : 0;
        __syncthreads();
        part[t] += v;
        __syncthreads();
    }
    int run = (t == 0) ? 0 : part[t - 1];
    int* st = starts + bg * (HWc + 1);
    int* cu = cursor + (bg << 14);
    for (int i = 0; i < 64; ++i){
        st[base + i] = run;
        cu[base + i] = run;
        run += cs[base + i];
    }
    if (t == 255) st[HWc] = run;
}

__global__ __launch_bounds__(256) void k_fill(const int* __restrict__ ci,
                                              int* __restrict__ cursor,
                                              int* __restrict__ plist){
    int idx = blockIdx.x*256 + threadIdx.x;
    if (idx >= Bb*3*Nn) return;
    int n = idx & (Nn-1);
    int bg = idx >> 15;
    int cell = min(max(ci[idx], 0), HWc-1);
    int pos = atomicAdd(&cursor[(bg<<14) + cell], 1);
    plist[(bg<<15) + pos] = n;
}

__global__ __launch_bounds__(256) void k_wcvt(const float* __restrict__ w1,
                                              const float* __restrict__ w2,
                                              unsigned short* __restrict__ W1b,
                                              unsigned short* __restrict__ W2b){
    int idx = blockIdx.x*256 + threadIdx.x;
    if (idx >= 4*Cc*Cc) return;
    W1b[idx] = f2b(w1[idx]);
    W2b[idx] = f2b(w2[idx]);
}

// ---------------- K1a: LayerNorm(smix) * wpt -> rbuf [b][n][c] fp16 ----------------
__global__ __launch_bounds__(256) void k1a_ln(const float* __restrict__ tok,
                                              const float* __restrict__ wpt,
                                              const float* __restrict__ lng,
                                              const float* __restrict__ lnb,
                                              __half* __restrict__ rbuf, int g){
    __shared__ float lg[Cc], lb[Cc];
    int t = threadIdx.x;
    lg[t] = lng[t];
    lb[t] = lnb[t];
    __syncthreads();
    int b = blockIdx.x >> 7;               // 128 blocks per batch, 256 points each
    int p = ((blockIdx.x & 127) << 8) + t;
    const float* tb = tok + ((size_t)b << 8)*Nn + p;
    float sum = 0.f, sq = 0.f;
    for (int c = 0; c < Cc; ++c){
        float x = tb[(size_t)c << 15];
        sum += x; sq += x*x;
    }
    float m = sum * (1.f/256.f);
    float v = sq * (1.f/256.f) - m*m;
    float r = rsqrtf(fmaxf(v, 0.f) + 1e-5f);
    float wv = wpt[(b*3 + g)*Nn + p];
    unsigned short* rb = (unsigned short*)rbuf + ((size_t)((b << 15) + p) << 8);
    for (int c0 = 0; c0 < Cc; c0 += 8){
        ushort8v u;
        #pragma unroll
        for (int j = 0; j < 8; ++j){
            int c = c0 + j;
            float x = tb[(size_t)c << 15];
            float h = ((x - m)*r*lg[c] + lb[c]) * wv;
            u[j] = __half_as_ushort(__float2half(h));
        }
        *(ushort8v*)(rb + c0) = u;
    }
}

// ---------------- K1b: CSR gather rbuf -> grid [b][c][hw], no atomics ----------------
__global__ __launch_bounds__(256) void k1b_gather(const __half* __restrict__ rbuf,
                                                  const int* __restrict__ starts,
                                                  const int* __restrict__ plist,
                                                  float* __restrict__ grid, int g){
    int t = threadIdx.x;                   // channel
    int bi = blockIdx.x;                   // Bb * (HW/16)
    int b = bi >> 10;
    int cell0 = (bi & 1023) << 4;
    int bg = b*3 + g;
    const int* st = starts + bg*(HWc + 1) + cell0;
    const int* pl = plist + (bg << 15);
    const __half* rb = rbuf + (((size_t)b << 15) << 8);
    float acc[16];
    int s0 = st[0];
    #pragma unroll
    for (int q = 0; q < 16; ++q){
        int s1 = st[q + 1];
        float a = 0.f;
        for (int j = s0; j < s1; ++j){
            int p = pl[j];
            a += __half2float(rb[((size_t)p << 8) + t]);
        }
        acc[q] = a;
        s0 = s1;
    }
    float* go = grid + ((size_t)((b << 8) + t))*HWc + cell0;
    #pragma unroll
    for (int q = 0; q < 16; q += 4){
        floatx4 w4 = { acc[q], acc[q+1], acc[q+2], acc[q+3] };
        *(floatx4*)(go + q) = w4;
    }
}

// ---------------- K2: fused dwconv3 -> relu -> dwconv3 (+skip) + BN partial sums ----------------
__global__ __launch_bounds__(256) void k2_conv(const float* __restrict__ grid,
                                               const float* __restrict__ skip,
                                               float* __restrict__ plane,
                                               const float* __restrict__ w1, const float* __restrict__ b1,
                                               const float* __restrict__ w2, const float* __restrict__ b2,
                                               const float* __restrict__ asc,
                                               float* __restrict__ bnS, float* __restrict__ bnQ,
                                               int useskip){
    __shared__ float it[36*132];
    __shared__ float mid[34*132];
    int tid = threadIdx.x;
    int bi = blockIdx.x;
    int rt = bi & 3;
    int bc = bi >> 2;              // b*256+c
    int c = bc & 255;
    int r0 = rt << 5;
    const float* src = grid + (size_t)bc*HWc;
    const float* sk  = skip + (size_t)bc*HWc;
    for (int i = tid; i < 36*132; i += 256){
        int r = i / 132, cc = i - r*132;
        int gy = r0 - 2 + r, gx = cc - 2;
        float v = 0.f;
        if ((unsigned)gy < 128u && (unsigned)gx < 128u){
            int o = (gy << 7) + gx;
            v = src[o];
            if (useskip) v += sk[o];
        }
        it[i] = v;
    }
    float a1[9], a2[9];
    #pragma unroll
    for (int j = 0; j < 9; ++j){ a1[j] = w1[c*9+j]; a2[j] = w2[c*9+j]; }
    float bb1 = b1[c], bb2 = b2[c], sc = asc[c];
    __syncthreads();
    for (int i = tid; i < 34*130; i += 256){
        int r = i / 130, cc = i - r*130;
        int y = r0 - 1 + r, x = cc - 1;
        float v = 0.f;
        if ((unsigned)y < 128u && (unsigned)x < 128u){
            float s = 0.f;
            #pragma unroll
            for (int j = 0; j < 9; ++j) s += a1[j] * it[(r + j/3)*132 + cc + (j%3)];
            v = fmaxf(s + bb1, 0.f);
        }
        mid[r*132 + cc] = v;
    }
    __syncthreads();
    float ps = 0.f, pq = 0.f;
    float* dst = plane + (size_t)bc*HWc;
    for (int i = tid; i < 32*128; i += 256){
        int yy = i >> 7, x = i & 127;
        float s = 0.f;
        #pragma unroll
        for (int j = 0; j < 9; ++j) s += a2[j] * mid[(yy + j/3)*132 + x + (j%3)];
        float v = s + bb2;
        dst[((r0 + yy) << 7) + x] = v;
        float t = v * sc;
        ps += t; pq += t*t;
    }
    __syncthreads();
    it[tid] = ps; it[256 + tid] = pq;
    __syncthreads();
    for (int s2 = 128; s2 > 0; s2 >>= 1){
        if (tid < s2){ it[tid] += it[tid+s2]; it[256+tid] += it[256+tid+s2]; }
        __syncthreads();
    }
    if (tid == 0){
        atomicAdd(&bnS[c], it[0]);
        atomicAdd(&bnQ[c], it[256]);
    }
}

// ---------------- K2b: fold BN into per-channel affine P,Q ----------------
__global__ __launch_bounds__(256) void k2b_bn(const float* __restrict__ bnS, const float* __restrict__ bnQ,
                                              const float* __restrict__ asc,
                                              const float* __restrict__ bng, const float* __restrict__ bnb,
                                              float* __restrict__ P, float* __restrict__ Q){
    int c = threadIdx.x;
    float mean = bnS[c] * (1.f/32768.f);
    float var  = bnQ[c] * (1.f/32768.f) - mean*mean;
    float inv  = rsqrtf(fmaxf(var, 0.f) + 1e-5f) * bng[c];
    P[c] = asc[c] * inv;
    Q[c] = bnb[c] - mean * inv;
}

// ---------------- K3t: apply sigmoid gate + transpose plane -> attp [b][hw][c] ----------------
__global__ __launch_bounds__(256) void k3t_att_t(const float* __restrict__ plane,
                                                 const float* __restrict__ P, const float* __restrict__ Q,
                                                 float* __restrict__ attp){
    __shared__ float t[32*33];
    int tid = threadIdx.x;
    int tx = tid & 31, ty = tid >> 5;
    int bi = blockIdx.x;
    int ht = bi & 511;
    int ct = (bi >> 9) & 7;
    int b  = bi >> 12;
    int c0 = ct << 5, h0 = ht << 5;
    for (int r = ty; r < 32; r += 8){
        int c = c0 + r;
        float v = plane[(((size_t)b << 8) + c)*HWc + h0 + tx];
        float s = 1.f / (1.f + __expf(-(P[c]*v + Q[c])));
        t[r*33 + tx] = s * v;
    }
    __syncthreads();
    for (int r = ty; r < 32; r += 8){
        attp[(((size_t)b << 14) + h0 + r)*Cc + c0 + tx] = t[tx*33 + r];
    }
}

// ---------------- K4: spatial-add + cmix LN + MFMA mm1(relu) + mm2 + residual ----------------
__global__ __launch_bounds__(256) void k4_cmix(const float* __restrict__ tsrc,
                                               const float* __restrict__ attp,
                                               const int* __restrict__ ci,
                                               const unsigned short* __restrict__ W1,
                                               const unsigned short* __restrict__ W2,
                                               const float* __restrict__ lng, const float* __restrict__ lnb,
                                               const float* __restrict__ b1, const float* __restrict__ b2,
                                               const float* __restrict__ csc,
                                               float* __restrict__ out, int g){
    __shared__ __align__(16) unsigned short hbuf[8448];   // h [p][c] stride 264; later h2 [c][p] stride 33
    __shared__ __align__(16) unsigned short h1buf[8448];  // h1 [p][c] stride 264
    __shared__ unsigned short rls[8448];                  // r [c][p] stride 33 (bf16)
    __shared__ float reds[256], redq[256];
    __shared__ float m_s[32], r_s[32];
    __shared__ int cell_s[32];
    __shared__ float lng_s[Cc], lnb_s[Cc], b1_s[Cc], b2s_s[Cc], cs_s[Cc];

    int tid = threadIdx.x;
    int bi = blockIdx.x;
    int b = bi >> 10;              // 1024 blocks per batch, 32 points each
    int p0 = (bi & 1023) << 5;

    lng_s[tid] = lng[tid];
    lnb_s[tid] = lnb[tid];
    b1_s[tid] = b1[tid];
    float cv = csc[tid];
    cs_s[tid] = cv;
    b2s_s[tid] = b2[tid] * cv;
    if (tid < 32){
        int cc = ci[(b*3 + g)*Nn + p0 + tid];
        cell_s[tid] = min(max(cc, 0), HWc-1);
    }
    __syncthreads();

    // stage gathered spatial contribution r[c][p] (coalesced rows of transposed attp)
    const float* ap = attp + (size_t)b * ((size_t)HWc * Cc);
    #pragma unroll 4
    for (int pp = 0; pp < 32; ++pp){
        rls[tid*33 + pp] = f2b(ap[(size_t)cell_s[pp]*Cc + tid]);
    }
    __syncthreads();

    int p = tid & 31;
    int cg = tid >> 5;             // 8 channel groups; thread covers c = cg + 8k
    float vreg[32];
    float sum = 0.f, sq = 0.f;
    const float* tb = tsrc + ((size_t)b << 8)*Nn + p0 + p;
    #pragma unroll
    for (int k = 0; k < 32; ++k){
        int c = cg + (k << 3);
        float v = tb[(size_t)c << 15] + b2f(rls[c*33 + p]);
        vreg[k] = v; sum += v; sq += v*v;
    }
    reds[tid] = sum; redq[tid] = sq;
    __syncthreads();
    if (tid < 32){
        float s = 0.f, q = 0.f;
        #pragma unroll
        for (int j = 0; j < 8; ++j){ s += reds[j*32 + tid]; q += redq[j*32 + tid]; }
        float m = s * (1.f/256.f);
        float var = q * (1.f/256.f) - m*m;
        m_s[tid] = m;
        r_s[tid] = rsqrtf(fmaxf(var, 0.f) + 1e-5f);
    }
    __syncthreads();
    float mp = m_s[p], rp = r_s[p];
    #pragma unroll
    for (int k = 0; k < 32; ++k){
        int c = cg + (k << 3);
        float hn = (vreg[k] - mp)*rp*lng_s[c] + lnb_s[c];
        hbuf[p*264 + c] = f2b(hn);
    }
    __syncthreads();

    int lane = tid & 63;
    int w = tid >> 6;
    int l15 = lane & 15;
    int q4 = lane >> 4;
    floatx4 acc[4][2];
    #pragma unroll
    for (int mi = 0; mi < 4; ++mi)
        #pragma unroll
        for (int ni = 0; ni < 2; ++ni)
            acc[mi][ni] = (floatx4){0.f, 0.f, 0.f, 0.f};

    // mm1: h1 = relu(W1 @ h + b1)
    #pragma unroll
    for (int kk = 0; kk < 8; ++kk){
        int k0 = kk*32 + q4*8;
        bf16x8 bfr[2];
        #pragma unroll
        for (int ni = 0; ni < 2; ++ni)
            bfr[ni] = *(const bf16x8*)&hbuf[(ni*16 + l15)*264 + k0];
        #pragma unroll
        for (int mi = 0; mi < 4; ++mi){
            bf16x8 af = *(const bf16x8*)&W1[(size_t)(w*64 + mi*16 + l15)*Cc + k0];
            #pragma unroll
            for (int ni = 0; ni < 2; ++ni)
                acc[mi][ni] = __builtin_amdgcn_mfma_f32_16x16x32_bf16(af, bfr[ni], acc[mi][ni], 0, 0, 0);
        }
    }
    #pragma unroll
    for (int mi = 0; mi < 4; ++mi)
        #pragma unroll
        for (int ni = 0; ni < 2; ++ni)
            #pragma unroll
            for (int r = 0; r < 4; ++r){
                int m = w*64 + mi*16 + q4*4 + r;
                int nn = ni*16 + l15;
                float v = fmaxf(acc[mi][ni][r] + b1_s[m], 0.f);
                h1buf[nn*264 + m] = f2b(v);
            }
    __syncthreads();

    // mm2: h2 = (W2 @ h1 + b2) * cmix_scale  (bias+scale folded)
    #pragma unroll
    for (int mi = 0; mi < 4; ++mi)
        #pragma unroll
        for (int ni = 0; ni < 2; ++ni)
            acc[mi][ni] = (floatx4){0.f, 0.f, 0.f, 0.f};
    #pragma unroll
    for (int kk = 0; kk < 8; ++kk){
        int k0 = kk*32 + q4*8;
        bf16x8 bfr[2];
        #pragma unroll
        for (int ni = 0; ni < 2; ++ni)
            bfr[ni] = *(const bf16x8*)&h1buf[(ni*16 + l15)*264 + k0];
        #pragma unroll
        for (int mi = 0; mi < 4; ++mi){
            bf16x8 af = *(const bf16x8*)&W2[(size_t)(w*64 + mi*16 + l15)*Cc + k0];
            #pragma unroll
            for (int ni = 0; ni < 2; ++ni)
                acc[mi][ni] = __builtin_amdgcn_mfma_f32_16x16x32_bf16(af, bfr[ni], acc[mi][ni], 0, 0, 0);
        }
    }
    #pragma unroll
    for (int mi = 0; mi < 4; ++mi)
        #pragma unroll
        for (int ni = 0; ni < 2; ++ni)
            #pragma unroll
            for (int r = 0; r < 4; ++r){
                int m = w*64 + mi*16 + q4*4 + r;
                int nn = ni*16 + l15;
                float v = acc[mi][ni][r]*cs_s[m] + b2s_s[m];
                hbuf[m*33 + nn] = f2b(v);   // reuse hbuf as h2 [c][p]
            }
    __syncthreads();

    #pragma unroll
    for (int k = 0; k < 32; ++k){
        int c = cg + (k << 3);
        out[(((size_t)b << 8) + c)*Nn + p0 + p] = vreg[k] + b2f(hbuf[c*33 + p]);
    }
}

extern "C" void kernel_launch(void* const* d_in, const int* in_sizes, int n_in,
                              void* d_out, int out_size, void* d_ws, size_t ws_size,
                              hipStream_t stream){
    (void)in_sizes; (void)n_in; (void)out_size; (void)ws_size;
    const float* tokens  = (const float*)d_in[0];
    const int*   cellind = (const int*)d_in[1];
    const float* occ     = (const float*)d_in[2];
    const float* smix_g  = (const float*)d_in[3];
    const float* smix_b  = (const float*)d_in[4];
    const float* ffn_w1  = (const float*)d_in[5];
    const float* ffn_b1  = (const float*)d_in[6];
    const float* ffn_w2  = (const float*)d_in[7];
    const float* ffn_b2  = (const float*)d_in[8];
    const float* att_sc  = (const float*)d_in[9];
    const float* bn_g    = (const float*)d_in[10];
    const float* bn_b    = (const float*)d_in[11];
    const float* cm_g    = (const float*)d_in[12];
    const float* cm_b    = (const float*)d_in[13];
    const float* cw1     = (const float*)d_in[14];
    const float* cb1     = (const float*)d_in[15];
    const float* cw2     = (const float*)d_in[16];
    const float* cb2     = (const float*)d_in[17];
    const float* cscale  = (const float*)d_in[18];
    float* out = (float*)d_out;
    char* w = (char*)d_ws;

    const size_t GRID_BYTES = (size_t)Bb*Cc*HWc*4;   // 33554432
    float* grid   = (float*)(w);
    float* planeA = (float*)(w + GRID_BYTES);
    float* planeB = (float*)(w + 2*GRID_BYTES);
    __half* rbuf  = (__half*)planeB;                 // alias: dead between k1a and k2
    size_t o = 3*GRID_BYTES;
    float* fcounts = (float*)(w + o); o += (size_t)Bb*3*HWc*4;   // 393216
    int*   icounts = (int*)(w + o);   o += (size_t)Bb*3*HWc*4;   // 393216 (contiguous w/ fcounts for one memset)
    float* wptb   = (float*)(w + o); o += (size_t)Bb*3*Nn*4;     // 786432
    float* bnS    = (float*)(w + o);                             // 4 x 256 floats (S,Q,P,Qaff)
    float* bnQ    = bnS + 256;
    float* Pb     = bnS + 512;
    float* Qb     = bnS + 768;
    o += 4096;
    unsigned short* W1b = (unsigned short*)(w + o);
    unsigned short* W2b = W1b + 4*Cc*Cc;
    o += (size_t)2*4*Cc*Cc*2;
    int* startsb  = (int*)(w + o); o += (size_t)Bb*3*(HWc+1)*4;  // 393240
    int* cursors  = (int*)(w + o); o += (size_t)Bb*3*HWc*4;      // 393216
    int* plistb   = (int*)(w + o); o += (size_t)Bb*3*Nn*4;       // 786432

    // ---- setup (once per launch) ----
    hipMemsetAsync(fcounts, 0, (size_t)2*Bb*3*HWc*4, stream);    // fcounts + icounts
    k_count<<<(Bb*3*Nn)/256, 256, 0, stream>>>(cellind, occ, fcounts, icounts);
    k_wpt<<<(Bb*3*Nn)/256, 256, 0, stream>>>(cellind, occ, fcounts, wptb);
    k_scan<<<Bb*3, 256, 0, stream>>>(icounts, startsb, cursors);
    k_fill<<<(Bb*3*Nn)/256, 256, 0, stream>>>(cellind, cursors, plistb);
    k_wcvt<<<(4*Cc*Cc)/256, 256, 0, stream>>>(cw1, cw2, W1b, W2b);

    for (int d = 0; d < 4; ++d){
        int g = d % 3;
        int useskip = (d == 3) ? 1 : 0;
        float* plane = (d == 0) ? planeA : planeB;
        const float* tsrc = (d == 0) ? tokens : out;

        hipMemsetAsync(bnS, 0, 2048, stream);

        k1a_ln<<<Bb*(Nn/256), 256, 0, stream>>>(tsrc, wptb,
                                                smix_g + d*Cc, smix_b + d*Cc, rbuf, g);
        k1b_gather<<<Bb*(HWc/16), 256, 0, stream>>>(rbuf, startsb, plistb, grid, g);
        k2_conv<<<Bb*Cc*4, 256, 0, stream>>>(grid, planeA, plane,
                                             ffn_w1 + d*Cc*9, ffn_b1 + d*Cc,
                                             ffn_w2 + d*Cc*9, ffn_b2 + d*Cc,
                                             att_sc + d*Cc, bnS, bnQ, useskip);
        k2b_bn<<<1, 256, 0, stream>>>(bnS, bnQ, att_sc + d*Cc, bn_g + d*Cc, bn_b + d*Cc, Pb, Qb);
        // grid buffer is dead after k2_conv -> reuse it as the transposed gated plane
        k3t_att_t<<<Bb*8*512, 256, 0, stream>>>(plane, Pb, Qb, grid);
        k4_cmix<<<Bb*(Nn/32), 256, 0, stream>>>(tsrc, grid, cellind,
                                                W1b + (size_t)d*Cc*Cc, W2b + (size_t)d*Cc*Cc,
                                                cm_g + d*Cc, cm_b + d*Cc,
                                                cb1 + d*Cc, cb2 + d*Cc, cscale + d*Cc,
                                                out, g);
    }
}

// Round 3
// 887.391 us; speedup vs baseline: 4.5315x; 1.1359x over previous
//
#include <hip/hip_runtime.h>
#include <hip/hip_bf16.h>
#include <hip/hip_fp16.h>

#define Cc 256
#define Nn 32768
#define HWc 16384
#define Bb 2

typedef float floatx4 __attribute__((ext_vector_type(4)));
typedef short bf16x8 __attribute__((ext_vector_type(8)));
typedef unsigned short ushort8v __attribute__((ext_vector_type(8)));

__device__ __forceinline__ unsigned short f2b(float f){
    unsigned u = __float_as_uint(f);
    u += 0x7fff + ((u >> 16) & 1);
    return (unsigned short)(u >> 16);
}
__device__ __forceinline__ float b2f(unsigned short h){
    return __uint_as_float(((unsigned)h) << 16);
}
__device__ __forceinline__ unsigned short f2h(float f){
    return __half_as_ushort(__float2half(f));
}
__device__ __forceinline__ float h2f(unsigned short h){
    return __half2float(__ushort_as_half(h));
}

// ---------------- setup kernels ----------------
__global__ __launch_bounds__(256) void k_count(const int* __restrict__ ci,
                                               const float* __restrict__ occ,
                                               float* __restrict__ fcounts,
                                               int* __restrict__ icounts){
    int idx = blockIdx.x*256 + threadIdx.x;
    if (idx >= Bb*3*Nn) return;
    int n = idx & (Nn-1);
    int bg = idx >> 15;           // b*3+g
    int b = bg / 3;
    int cell = min(max(ci[idx], 0), HWc-1);
    float o = occ[(b<<15) + n];
    atomicAdd(&fcounts[(bg<<14) + cell], o*o);
    atomicAdd(&icounts[(bg<<14) + cell], 1);
}

__global__ __launch_bounds__(256) void k_wpt(const int* __restrict__ ci,
                                             const float* __restrict__ occ,
                                             const float* __restrict__ fcounts,
                                             float* __restrict__ wpt){
    int idx = blockIdx.x*256 + threadIdx.x;
    if (idx >= Bb*3*Nn) return;
    int n = idx & (Nn-1);
    int bg = idx >> 15;
    int b = bg / 3;
    int cell = min(max(ci[idx], 0), HWc-1);
    float o = occ[(b<<15) + n];
    float cnt = fcounts[(bg<<14) + cell];
    wpt[idx] = o / (o*cnt + 1e-6f);
}

// exclusive prefix scan of per-cell int counts -> starts[HW+1], cursors copy
__global__ __launch_bounds__(256) void k_scan(const int* __restrict__ ic,
                                              int* __restrict__ starts,
                                              int* __restrict__ cursor){
    __shared__ int part[256];
    int bg = blockIdx.x;          // 0..5
    int t = threadIdx.x;
    const int* cs = ic + (bg << 14);
    int base = t * 64;
    int s = 0;
    for (int i = 0; i < 64; ++i) s += cs[base + i];
    part[t] = s;
    __syncthreads();
    for (int off = 1; off < 256; off <<= 1){
        int v = (t >= off) ? part[t - off] : 0;
        __syncthreads();
        part[t] += v;
        __syncthreads();
    }
    int run = (t == 0) ? 0 : part[t - 1];
    int* st = starts + bg * (HWc + 1);
    int* cu = cursor + (bg << 14);
    for (int i = 0; i < 64; ++i){
        st[base + i] = run;
        cu[base + i] = run;
        run += cs[base + i];
    }
    if (t == 255) st[HWc] = run;
}

__global__ __launch_bounds__(256) void k_fill(const int* __restrict__ ci,
                                              int* __restrict__ cursor,
                                              int* __restrict__ plist){
    int idx = blockIdx.x*256 + threadIdx.x;
    if (idx >= Bb*3*Nn) return;
    int n = idx & (Nn-1);
    int bg = idx >> 15;
    int cell = min(max(ci[idx], 0), HWc-1);
    int pos = atomicAdd(&cursor[(bg<<14) + cell], 1);
    plist[(bg<<15) + pos] = n;
}

__global__ __launch_bounds__(256) void k_wcvt(const float* __restrict__ w1,
                                              const float* __restrict__ w2,
                                              unsigned short* __restrict__ W1b,
                                              unsigned short* __restrict__ W2b){
    int idx = blockIdx.x*256 + threadIdx.x;
    if (idx >= 4*Cc*Cc) return;
    W1b[idx] = f2b(w1[idx]);
    W2b[idx] = f2b(w2[idx]);
}

// ---------------- K1a (depth 0 only): LayerNorm(smix) * wpt -> rbuf [b][n][c] fp16 ----------------
__global__ __launch_bounds__(256) void k1a_ln(const float* __restrict__ tok,
                                              const float* __restrict__ wpt,
                                              const float* __restrict__ lng,
                                              const float* __restrict__ lnb,
                                              unsigned short* __restrict__ rbuf, int g){
    __shared__ float lg[Cc], lb[Cc];
    int t = threadIdx.x;
    lg[t] = lng[t];
    lb[t] = lnb[t];
    __syncthreads();
    int b = blockIdx.x >> 7;               // 128 blocks per batch, 256 points each
    int p = ((blockIdx.x & 127) << 8) + t;
    const float* tb = tok + ((size_t)b << 8)*Nn + p;
    float sum = 0.f, sq = 0.f;
    for (int c = 0; c < Cc; ++c){
        float x = tb[(size_t)c << 15];
        sum += x; sq += x*x;
    }
    float m = sum * (1.f/256.f);
    float v = sq * (1.f/256.f) - m*m;
    float r = rsqrtf(fmaxf(v, 0.f) + 1e-5f);
    float wv = wpt[(b*3 + g)*Nn + p];
    unsigned short* rb = rbuf + ((size_t)((b << 15) + p) << 8);
    for (int c0 = 0; c0 < Cc; c0 += 8){
        ushort8v u;
        #pragma unroll
        for (int j = 0; j < 8; ++j){
            int c = c0 + j;
            float x = tb[(size_t)c << 15];
            float h = ((x - m)*r*lg[c] + lb[c]) * wv;
            u[j] = f2h(h);
        }
        *(ushort8v*)(rb + c0) = u;
    }
}

// ---------------- K1b: CSR gather rbuf -> grid fp16 [b][c][hw], no atomics ----------------
__global__ __launch_bounds__(256) void k1b_gather(const unsigned short* __restrict__ rbuf,
                                                  const int* __restrict__ starts,
                                                  const int* __restrict__ plist,
                                                  unsigned short* __restrict__ grid, int g){
    int t = threadIdx.x;                   // channel
    int bi = blockIdx.x;                   // Bb * (HW/16)
    int b = bi >> 10;
    int cell0 = (bi & 1023) << 4;
    int bg = b*3 + g;
    const int* st = starts + bg*(HWc + 1) + cell0;
    const int* pl = plist + (bg << 15);
    const unsigned short* rb = rbuf + (((size_t)b << 15) << 8);
    float acc[16];
    int s0 = st[0];
    #pragma unroll
    for (int q = 0; q < 16; ++q){
        int s1 = st[q + 1];
        float a = 0.f;
        for (int j = s0; j < s1; ++j){
            int p = pl[j];
            a += h2f(rb[((size_t)p << 8) + t]);
        }
        acc[q] = a;
        s0 = s1;
    }
    unsigned short* go = grid + ((size_t)((b << 8) + t))*HWc + cell0;
    #pragma unroll
    for (int q = 0; q < 16; q += 8){
        ushort8v u;
        #pragma unroll
        for (int j = 0; j < 8; ++j) u[j] = f2h(acc[q+j]);
        *(ushort8v*)(go + q) = u;
    }
}

// ---------------- K2: fused dwconv3 -> relu -> dwconv3 (+skip) + BN partial sums (fp16 IO) ------
__global__ __launch_bounds__(256) void k2_conv(const unsigned short* __restrict__ grid,
                                               const unsigned short* __restrict__ skip,
                                               unsigned short* __restrict__ plane,
                                               const float* __restrict__ w1, const float* __restrict__ b1,
                                               const float* __restrict__ w2, const float* __restrict__ b2,
                                               const float* __restrict__ asc,
                                               float* __restrict__ bnS, float* __restrict__ bnQ,
                                               int useskip){
    __shared__ float it[36*132];
    __shared__ float mid[34*132];
    int tid = threadIdx.x;
    int bi = blockIdx.x;
    int rt = bi & 3;
    int bc = bi >> 2;              // b*256+c
    int c = bc & 255;
    int r0 = rt << 5;
    const unsigned short* src = grid + (size_t)bc*HWc;
    const unsigned short* sk  = skip + (size_t)bc*HWc;
    for (int i = tid; i < 36*132; i += 256){
        int r = i / 132, cc = i - r*132;
        int gy = r0 - 2 + r, gx = cc - 2;
        float v = 0.f;
        if ((unsigned)gy < 128u && (unsigned)gx < 128u){
            int o = (gy << 7) + gx;
            v = h2f(src[o]);
            if (useskip) v += h2f(sk[o]);
        }
        it[i] = v;
    }
    float a1[9], a2[9];
    #pragma unroll
    for (int j = 0; j < 9; ++j){ a1[j] = w1[c*9+j]; a2[j] = w2[c*9+j]; }
    float bb1 = b1[c], bb2 = b2[c], sc = asc[c];
    __syncthreads();
    for (int i = tid; i < 34*130; i += 256){
        int r = i / 130, cc = i - r*130;
        int y = r0 - 1 + r, x = cc - 1;
        float v = 0.f;
        if ((unsigned)y < 128u && (unsigned)x < 128u){
            float s = 0.f;
            #pragma unroll
            for (int j = 0; j < 9; ++j) s += a1[j] * it[(r + j/3)*132 + cc + (j%3)];
            v = fmaxf(s + bb1, 0.f);
        }
        mid[r*132 + cc] = v;
    }
    __syncthreads();
    float ps = 0.f, pq = 0.f;
    unsigned short* dst = plane + (size_t)bc*HWc;
    for (int i = tid; i < 32*128; i += 256){
        int yy = i >> 7, x = i & 127;
        float s = 0.f;
        #pragma unroll
        for (int j = 0; j < 9; ++j) s += a2[j] * mid[(yy + j/3)*132 + x + (j%3)];
        float v = s + bb2;
        dst[((r0 + yy) << 7) + x] = f2h(v);
        float t = v * sc;
        ps += t; pq += t*t;
    }
    __syncthreads();
    it[tid] = ps; it[256 + tid] = pq;
    __syncthreads();
    for (int s2 = 128; s2 > 0; s2 >>= 1){
        if (tid < s2){ it[tid] += it[tid+s2]; it[256+tid] += it[256+tid+s2]; }
        __syncthreads();
    }
    if (tid == 0){
        atomicAdd(&bnS[c], it[0]);
        atomicAdd(&bnQ[c], it[256]);
    }
}

// ---------------- K2b: fold BN into per-channel affine P,Q ----------------
__global__ __launch_bounds__(256) void k2b_bn(const float* __restrict__ bnS, const float* __restrict__ bnQ,
                                              const float* __restrict__ asc,
                                              const float* __restrict__ bng, const float* __restrict__ bnb,
                                              float* __restrict__ P, float* __restrict__ Q){
    int c = threadIdx.x;
    float mean = bnS[c] * (1.f/32768.f);
    float var  = bnQ[c] * (1.f/32768.f) - mean*mean;
    float inv  = rsqrtf(fmaxf(var, 0.f) + 1e-5f) * bng[c];
    P[c] = asc[c] * inv;
    Q[c] = bnb[c] - mean * inv;
}

// ---------------- K3t: sigmoid gate + transpose plane -> attp fp16 [b][hw][c] ----------------
__global__ __launch_bounds__(256) void k3t_att_t(const unsigned short* __restrict__ plane,
                                                 const float* __restrict__ P, const float* __restrict__ Q,
                                                 unsigned short* __restrict__ attp){
    __shared__ float t[32*33];
    int tid = threadIdx.x;
    int tx = tid & 31, ty = tid >> 5;
    int bi = blockIdx.x;
    int ht = bi & 511;
    int ct = (bi >> 9) & 7;
    int b  = bi >> 12;
    int c0 = ct << 5, h0 = ht << 5;
    for (int r = ty; r < 32; r += 8){
        int c = c0 + r;
        float v = h2f(plane[(((size_t)b << 8) + c)*HWc + h0 + tx]);
        float s = 1.f / (1.f + __expf(-(P[c]*v + Q[c])));
        t[r*33 + tx] = s * v;
    }
    __syncthreads();
    for (int r = ty; r < 32; r += 8){
        attp[(((size_t)b << 14) + h0 + r)*Cc + c0 + tx] = f2h(t[tx*33 + r]);
    }
}

// ---------------- K4: gather + cmix LN + MFMA mm1(relu) + mm2 + residual + next-depth LN ----------
__global__ __launch_bounds__(256) void k4_cmix(const float* __restrict__ tsrc,
                                               const unsigned short* __restrict__ attp,  // fp16 [b][hw][c]
                                               const int* __restrict__ ci,
                                               const unsigned short* __restrict__ W1,
                                               const unsigned short* __restrict__ W2,
                                               const float* __restrict__ lng, const float* __restrict__ lnb,
                                               const float* __restrict__ b1, const float* __restrict__ b2,
                                               const float* __restrict__ csc,
                                               const float* __restrict__ lng2, const float* __restrict__ lnb2,
                                               const float* __restrict__ wptb,
                                               float* __restrict__ out,
                                               unsigned short* __restrict__ rbufn,      // fp16 [b][n][c]
                                               int g, int g2, int donext){
    // arena A: r [p][282], later h1 [p][280], later h_next [p][282]
    // arena B: h [p][280], later h2 [c][34]
    __shared__ __align__(16) unsigned short ldsA[9024];
    __shared__ __align__(16) unsigned short ldsB[9024];
    __shared__ float reds[256], redq[256];
    __shared__ float m_s[32], r_s[32];
    __shared__ int cell_s[32];
    __shared__ float lng_s[Cc], lnb_s[Cc], b1_s[Cc], b2s_s[Cc], cs_s[Cc], g2g_s[Cc], g2b_s[Cc];

    int tid = threadIdx.x;
    int bi = blockIdx.x;
    int b = bi >> 10;              // 1024 blocks per batch, 32 points each
    int p0 = (bi & 1023) << 5;

    lng_s[tid] = lng[tid];
    lnb_s[tid] = lnb[tid];
    b1_s[tid]  = b1[tid];
    float cv = csc[tid];
    cs_s[tid]  = cv;
    b2s_s[tid] = b2[tid] * cv;
    g2g_s[tid] = lng2[tid];
    g2b_s[tid] = lnb2[tid];
    if (tid < 32){
        int cc = ci[(b*3 + g)*Nn + p0 + tid];
        cell_s[tid] = min(max(cc, 0), HWc-1);
    }
    __syncthreads();

    // ---- gather r (raw fp16) -> ldsA [p][c] stride 282, vectorized uint ----
    {
        const unsigned short* ap = attp + (((size_t)b) << 14)*Cc;
        int tt = tid & 127;
        int hi = tid >> 7;
        #pragma unroll
        for (int it8 = 0; it8 < 16; ++it8){
            int pp = it8*2 + hi;
            unsigned u = *(const unsigned*)&ap[(size_t)cell_s[pp]*Cc + 2*tt];
            *(unsigned*)&ldsA[pp*282 + 2*tt] = u;
        }
    }
    __syncthreads();

    int p  = tid & 31;
    int cg = tid >> 5;             // 8 groups; thread covers c = cg*32 + k, k=0..31
    int c0 = cg << 5;
    float vreg[32];
    float sum = 0.f, sq = 0.f;
    const float* tb = tsrc + ((size_t)b << 8)*Nn + p0 + p;
    #pragma unroll
    for (int k2i = 0; k2i < 16; ++k2i){
        int c = c0 + 2*k2i;
        unsigned u = *(const unsigned*)&ldsA[p*282 + c];
        float v0 = tb[(size_t)c << 15]     + h2f((unsigned short)(u & 0xffffu));
        float v1 = tb[(size_t)(c+1) << 15] + h2f((unsigned short)(u >> 16));
        vreg[2*k2i]   = v0;
        vreg[2*k2i+1] = v1;
        sum += v0 + v1; sq += v0*v0 + v1*v1;
    }
    reds[tid] = sum; redq[tid] = sq;
    __syncthreads();
    if (tid < 32){
        float s = 0.f, q = 0.f;
        #pragma unroll
        for (int j = 0; j < 8; ++j){ s += reds[j*32 + tid]; q += redq[j*32 + tid]; }
        float m = s * (1.f/256.f);
        float var = q * (1.f/256.f) - m*m;
        m_s[tid] = m;
        r_s[tid] = rsqrtf(fmaxf(var, 0.f) + 1e-5f);
    }
    __syncthreads();
    float mp = m_s[p], rp = r_s[p];
    #pragma unroll
    for (int k2i = 0; k2i < 16; ++k2i){
        int c = c0 + 2*k2i;
        float h0 = (vreg[2*k2i]   - mp)*rp*lng_s[c]   + lnb_s[c];
        float h1 = (vreg[2*k2i+1] - mp)*rp*lng_s[c+1] + lnb_s[c+1];
        unsigned u = (unsigned)f2b(h0) | ((unsigned)f2b(h1) << 16);
        *(unsigned*)&ldsB[p*280 + c] = u;
    }
    __syncthreads();

    int lane = tid & 63;
    int w = tid >> 6;
    int l15 = lane & 15;
    int q4 = lane >> 4;
    floatx4 acc[4][2];
    #pragma unroll
    for (int mi = 0; mi < 4; ++mi)
        #pragma unroll
        for (int ni = 0; ni < 2; ++ni)
            acc[mi][ni] = (floatx4){0.f, 0.f, 0.f, 0.f};

    // mm1: h1 = relu(W1 @ h + b1)
    #pragma unroll
    for (int kk = 0; kk < 8; ++kk){
        int k0 = kk*32 + q4*8;
        bf16x8 bfr[2];
        #pragma unroll
        for (int ni = 0; ni < 2; ++ni)
            bfr[ni] = *(const bf16x8*)&ldsB[(ni*16 + l15)*280 + k0];
        #pragma unroll
        for (int mi = 0; mi < 4; ++mi){
            bf16x8 af = *(const bf16x8*)&W1[(size_t)(w*64 + mi*16 + l15)*Cc + k0];
            #pragma unroll
            for (int ni = 0; ni < 2; ++ni)
                acc[mi][ni] = __builtin_amdgcn_mfma_f32_16x16x32_bf16(af, bfr[ni], acc[mi][ni], 0, 0, 0);
        }
    }
    #pragma unroll
    for (int mi = 0; mi < 4; ++mi)
        #pragma unroll
        for (int ni = 0; ni < 2; ++ni)
            #pragma unroll
            for (int r = 0; r < 4; ++r){
                int m = w*64 + mi*16 + q4*4 + r;
                int nn = ni*16 + l15;
                float v = fmaxf(acc[mi][ni][r] + b1_s[m], 0.f);
                ldsA[nn*280 + m] = f2b(v);
            }
    __syncthreads();

    // mm2: h2 = (W2 @ h1)*cs + b2*cs
    #pragma unroll
    for (int mi = 0; mi < 4; ++mi)
        #pragma unroll
        for (int ni = 0; ni < 2; ++ni)
            acc[mi][ni] = (floatx4){0.f, 0.f, 0.f, 0.f};
    #pragma unroll
    for (int kk = 0; kk < 8; ++kk){
        int k0 = kk*32 + q4*8;
        bf16x8 bfr[2];
        #pragma unroll
        for (int ni = 0; ni < 2; ++ni)
            bfr[ni] = *(const bf16x8*)&ldsA[(ni*16 + l15)*280 + k0];
        #pragma unroll
        for (int mi = 0; mi < 4; ++mi){
            bf16x8 af = *(const bf16x8*)&W2[(size_t)(w*64 + mi*16 + l15)*Cc + k0];
            #pragma unroll
            for (int ni = 0; ni < 2; ++ni)
                acc[mi][ni] = __builtin_amdgcn_mfma_f32_16x16x32_bf16(af, bfr[ni], acc[mi][ni], 0, 0, 0);
        }
    }
    #pragma unroll
    for (int mi = 0; mi < 4; ++mi)
        #pragma unroll
        for (int ni = 0; ni < 2; ++ni)
            #pragma unroll
            for (int r = 0; r < 4; ++r){
                int m = w*64 + mi*16 + q4*4 + r;
                int nn = ni*16 + l15;
                float v = acc[mi][ni][r]*cs_s[m] + b2s_s[m];
                ldsB[m*34 + nn] = f2b(v);   // h2 [c][p] stride 34
            }
    __syncthreads();

    // ---- final tokens + out write + (optional) next-depth LN*wpt -> rbuf ----
    float sum2 = 0.f, sq2 = 0.f;
    float* ob = out + ((size_t)b << 8)*Nn + p0 + p;
    #pragma unroll
    for (int k = 0; k < 32; ++k){
        int c = c0 + k;
        float v = vreg[k] + b2f(ldsB[c*34 + p]);
        vreg[k] = v;
        ob[(size_t)c << 15] = v;
        sum2 += v; sq2 += v*v;
    }
    if (donext){
        reds[tid] = sum2; redq[tid] = sq2;
        __syncthreads();
        if (tid < 32){
            float s = 0.f, q = 0.f;
            #pragma unroll
            for (int j = 0; j < 8; ++j){ s += reds[j*32 + tid]; q += redq[j*32 + tid]; }
            float m = s * (1.f/256.f);
            float var = q * (1.f/256.f) - m*m;
            m_s[tid] = m;
            r_s[tid] = rsqrtf(fmaxf(var, 0.f) + 1e-5f);
        }
        __syncthreads();
        float m2 = m_s[p], rr2 = r_s[p];
        float wv2 = wptb[(b*3 + g2)*Nn + p0 + p];
        #pragma unroll
        for (int k2i = 0; k2i < 16; ++k2i){
            int c = c0 + 2*k2i;
            float h0 = ((vreg[2*k2i]   - m2)*rr2*g2g_s[c]   + g2b_s[c])   * wv2;
            float h1 = ((vreg[2*k2i+1] - m2)*rr2*g2g_s[c+1] + g2b_s[c+1]) * wv2;
            unsigned u = (unsigned)f2h(h0) | ((unsigned)f2h(h1) << 16);
            *(unsigned*)&ldsA[p*282 + c] = u;
        }
        __syncthreads();
        int tt = tid & 127;
        int hi = tid >> 7;
        unsigned short* rb = rbufn + (((size_t)(b << 15) + p0)) * Cc;
        #pragma unroll
        for (int it8 = 0; it8 < 16; ++it8){
            int row = it8*2 + hi;
            unsigned u = *(const unsigned*)&ldsA[row*282 + 2*tt];
            *(unsigned*)&rb[(size_t)row*Cc + 2*tt] = u;
        }
    }
}

extern "C" void kernel_launch(void* const* d_in, const int* in_sizes, int n_in,
                              void* d_out, int out_size, void* d_ws, size_t ws_size,
                              hipStream_t stream){
    (void)in_sizes; (void)n_in; (void)out_size; (void)ws_size;
    const float* tokens  = (const float*)d_in[0];
    const int*   cellind = (const int*)d_in[1];
    const float* occ     = (const float*)d_in[2];
    const float* smix_g  = (const float*)d_in[3];
    const float* smix_b  = (const float*)d_in[4];
    const float* ffn_w1  = (const float*)d_in[5];
    const float* ffn_b1  = (const float*)d_in[6];
    const float* ffn_w2  = (const float*)d_in[7];
    const float* ffn_b2  = (const float*)d_in[8];
    const float* att_sc  = (const float*)d_in[9];
    const float* bn_g    = (const float*)d_in[10];
    const float* bn_b    = (const float*)d_in[11];
    const float* cm_g    = (const float*)d_in[12];
    const float* cm_b    = (const float*)d_in[13];
    const float* cw1     = (const float*)d_in[14];
    const float* cb1     = (const float*)d_in[15];
    const float* cw2     = (const float*)d_in[16];
    const float* cb2     = (const float*)d_in[17];
    const float* cscale  = (const float*)d_in[18];
    float* out = (float*)d_out;
    char* w = (char*)d_ws;

    const size_t HGRID_BYTES = (size_t)Bb*Cc*HWc*2;          // 16777216
    unsigned short* grid_h  = (unsigned short*)(w);
    unsigned short* attp_h  = grid_h;                        // alias: grid dead after k2
    unsigned short* planeA  = (unsigned short*)(w + HGRID_BYTES);
    unsigned short* planeB  = (unsigned short*)(w + 2*HGRID_BYTES);
    unsigned short* rbuf    = (unsigned short*)(w + 3*HGRID_BYTES);  // [b][n][c] fp16, 33.5 MB
    size_t o = 3*HGRID_BYTES + (size_t)Bb*Nn*Cc*2;
    float* fcounts = (float*)(w + o); o += (size_t)Bb*3*HWc*4;
    int*   icounts = (int*)(w + o);   o += (size_t)Bb*3*HWc*4;
    float* wptb   = (float*)(w + o); o += (size_t)Bb*3*Nn*4;
    float* bnS    = (float*)(w + o);
    float* bnQ    = bnS + 256;
    float* Pb     = bnS + 512;
    float* Qb     = bnS + 768;
    o += 4096;
    unsigned short* W1b = (unsigned short*)(w + o);
    unsigned short* W2b = W1b + 4*Cc*Cc;
    o += (size_t)2*4*Cc*Cc*2;
    int* startsb  = (int*)(w + o); o += (size_t)Bb*3*(HWc+1)*4;
    int* cursors  = (int*)(w + o); o += (size_t)Bb*3*HWc*4;
    int* plistb   = (int*)(w + o); o += (size_t)Bb*3*Nn*4;

    // ---- setup (once per launch) ----
    hipMemsetAsync(fcounts, 0, (size_t)2*Bb*3*HWc*4, stream);
    k_count<<<(Bb*3*Nn)/256, 256, 0, stream>>>(cellind, occ, fcounts, icounts);
    k_wpt<<<(Bb*3*Nn)/256, 256, 0, stream>>>(cellind, occ, fcounts, wptb);
    k_scan<<<Bb*3, 256, 0, stream>>>(icounts, startsb, cursors);
    k_fill<<<(Bb*3*Nn)/256, 256, 0, stream>>>(cellind, cursors, plistb);
    k_wcvt<<<(4*Cc*Cc)/256, 256, 0, stream>>>(cw1, cw2, W1b, W2b);

    // depth-0 rbuf from input tokens
    k1a_ln<<<Bb*(Nn/256), 256, 0, stream>>>(tokens, wptb, smix_g, smix_b, rbuf, 0);

    for (int d = 0; d < 4; ++d){
        int g = d % 3;
        int g2 = (d + 1) % 3;
        int donext = (d < 3) ? 1 : 0;
        int useskip = (d == 3) ? 1 : 0;
        unsigned short* plane = (d == 0) ? planeA : planeB;
        const float* tsrc = (d == 0) ? tokens : out;
        int dn = (d + 1 < 4) ? d + 1 : d;   // next depth params (unused when donext=0)

        hipMemsetAsync(bnS, 0, 2048, stream);

        k1b_gather<<<Bb*(HWc/16), 256, 0, stream>>>(rbuf, startsb, plistb, grid_h, g);
        k2_conv<<<Bb*Cc*4, 256, 0, stream>>>(grid_h, planeA, plane,
                                             ffn_w1 + d*Cc*9, ffn_b1 + d*Cc,
                                             ffn_w2 + d*Cc*9, ffn_b2 + d*Cc,
                                             att_sc + d*Cc, bnS, bnQ, useskip);
        k2b_bn<<<1, 256, 0, stream>>>(bnS, bnQ, att_sc + d*Cc, bn_g + d*Cc, bn_b + d*Cc, Pb, Qb);
        k3t_att_t<<<Bb*8*512, 256, 0, stream>>>(plane, Pb, Qb, attp_h);
        k4_cmix<<<Bb*(Nn/32), 256, 0, stream>>>(tsrc, attp_h, cellind,
                                                W1b + (size_t)d*Cc*Cc, W2b + (size_t)d*Cc*Cc,
                                                cm_g + d*Cc, cm_b + d*Cc,
                                                cb1 + d*Cc, cb2 + d*Cc, cscale + d*Cc,
                                                smix_g + dn*Cc, smix_b + dn*Cc, wptb,
                                                out, rbuf, g, g2, donext);
    }
}

// Round 4
// 884.026 us; speedup vs baseline: 4.5487x; 1.0038x over previous
//
#include <hip/hip_runtime.h>
#include <hip/hip_bf16.h>
#include <hip/hip_fp16.h>

#define Cc 256
#define Nn 32768
#define HWc 16384
#define Bb 2

typedef float floatx4 __attribute__((ext_vector_type(4)));
typedef short bf16x8 __attribute__((ext_vector_type(8)));
typedef unsigned short ushort8v __attribute__((ext_vector_type(8)));
typedef unsigned short ushort4v __attribute__((ext_vector_type(4)));

__device__ __forceinline__ unsigned short f2b(float f){
    unsigned u = __float_as_uint(f);
    u += 0x7fff + ((u >> 16) & 1);
    return (unsigned short)(u >> 16);
}
__device__ __forceinline__ float b2f(unsigned short h){
    return __uint_as_float(((unsigned)h) << 16);
}
__device__ __forceinline__ unsigned short f2h(float f){
    return __half_as_ushort(__float2half(f));
}
__device__ __forceinline__ float h2f(unsigned short h){
    return __half2float(__ushort_as_half(h));
}

// ---------------- setup kernels ----------------
__global__ __launch_bounds__(256) void k_count(const int* __restrict__ ci,
                                               const float* __restrict__ occ,
                                               float* __restrict__ fcounts,
                                               int* __restrict__ icounts){
    int idx = blockIdx.x*256 + threadIdx.x;
    if (idx >= Bb*3*Nn) return;
    int n = idx & (Nn-1);
    int bg = idx >> 15;           // b*3+g
    int b = bg / 3;
    int cell = min(max(ci[idx], 0), HWc-1);
    float o = occ[(b<<15) + n];
    atomicAdd(&fcounts[(bg<<14) + cell], o*o);
    atomicAdd(&icounts[(bg<<14) + cell], 1);
}

__global__ __launch_bounds__(256) void k_wpt(const int* __restrict__ ci,
                                             const float* __restrict__ occ,
                                             const float* __restrict__ fcounts,
                                             float* __restrict__ wpt){
    int idx = blockIdx.x*256 + threadIdx.x;
    if (idx >= Bb*3*Nn) return;
    int n = idx & (Nn-1);
    int bg = idx >> 15;
    int b = bg / 3;
    int cell = min(max(ci[idx], 0), HWc-1);
    float o = occ[(b<<15) + n];
    float cnt = fcounts[(bg<<14) + cell];
    wpt[idx] = o / (o*cnt + 1e-6f);
}

// exclusive prefix scan of per-cell int counts -> starts[HW+1], cursors copy
__global__ __launch_bounds__(256) void k_scan(const int* __restrict__ ic,
                                              int* __restrict__ starts,
                                              int* __restrict__ cursor){
    __shared__ int part[256];
    int bg = blockIdx.x;          // 0..5
    int t = threadIdx.x;
    const int* cs = ic + (bg << 14);
    int base = t * 64;
    int s = 0;
    for (int i = 0; i < 64; ++i) s += cs[base + i];
    part[t] = s;
    __syncthreads();
    for (int off = 1; off < 256; off <<= 1){
        int v = (t >= off) ? part[t - off] : 0;
        __syncthreads();
        part[t] += v;
        __syncthreads();
    }
    int run = (t == 0) ? 0 : part[t - 1];
    int* st = starts + bg * (HWc + 1);
    int* cu = cursor + (bg << 14);
    for (int i = 0; i < 64; ++i){
        st[base + i] = run;
        cu[base + i] = run;
        run += cs[base + i];
    }
    if (t == 255) st[HWc] = run;
}

__global__ __launch_bounds__(256) void k_fill(const int* __restrict__ ci,
                                              int* __restrict__ cursor,
                                              int* __restrict__ plist){
    int idx = blockIdx.x*256 + threadIdx.x;
    if (idx >= Bb*3*Nn) return;
    int n = idx & (Nn-1);
    int bg = idx >> 15;
    int cell = min(max(ci[idx], 0), HWc-1);
    int pos = atomicAdd(&cursor[(bg<<14) + cell], 1);
    plist[(bg<<15) + pos] = n;
}

__global__ __launch_bounds__(256) void k_wcvt(const float* __restrict__ w1,
                                              const float* __restrict__ w2,
                                              unsigned short* __restrict__ W1b,
                                              unsigned short* __restrict__ W2b){
    int idx = blockIdx.x*256 + threadIdx.x;
    if (idx >= 4*Cc*Cc) return;
    W1b[idx] = f2b(w1[idx]);
    W2b[idx] = f2b(w2[idx]);
}

// ---------------- K1a (depth 0 only): LayerNorm(smix) * wpt -> rbuf [b][n][c] fp16 ----------------
__global__ __launch_bounds__(256) void k1a_ln(const float* __restrict__ tok,
                                              const float* __restrict__ wpt,
                                              const float* __restrict__ lng,
                                              const float* __restrict__ lnb,
                                              unsigned short* __restrict__ rbuf, int g){
    __shared__ float lg[Cc], lb[Cc];
    int t = threadIdx.x;
    lg[t] = lng[t];
    lb[t] = lnb[t];
    __syncthreads();
    int b = blockIdx.x >> 7;               // 128 blocks per batch, 256 points each
    int p = ((blockIdx.x & 127) << 8) + t;
    const float* tb = tok + ((size_t)b << 8)*Nn + p;
    float sum = 0.f, sq = 0.f;
    for (int c = 0; c < Cc; ++c){
        float x = tb[(size_t)c << 15];
        sum += x; sq += x*x;
    }
    float m = sum * (1.f/256.f);
    float v = sq * (1.f/256.f) - m*m;
    float r = rsqrtf(fmaxf(v, 0.f) + 1e-5f);
    float wv = wpt[(b*3 + g)*Nn + p];
    unsigned short* rb = rbuf + ((size_t)((b << 15) + p) << 8);
    for (int c0 = 0; c0 < Cc; c0 += 8){
        ushort8v u;
        #pragma unroll
        for (int j = 0; j < 8; ++j){
            int c = c0 + j;
            float x = tb[(size_t)c << 15];
            float h = ((x - m)*r*lg[c] + lb[c]) * wv;
            u[j] = f2h(h);
        }
        *(ushort8v*)(rb + c0) = u;
    }
}

// ---------------- K1b: CSR gather rbuf -> grid fp16 [b][c][hw], no atomics ----------------
__global__ __launch_bounds__(256) void k1b_gather(const unsigned short* __restrict__ rbuf,
                                                  const int* __restrict__ starts,
                                                  const int* __restrict__ plist,
                                                  unsigned short* __restrict__ grid, int g){
    int t = threadIdx.x;                   // channel
    int bi = blockIdx.x;                   // Bb * (HW/16)
    int b = bi >> 10;
    int cell0 = (bi & 1023) << 4;
    int bg = b*3 + g;
    const int* st = starts + bg*(HWc + 1) + cell0;
    const int* pl = plist + (bg << 15);
    const unsigned short* rb = rbuf + (((size_t)b << 15) << 8);
    float acc[16];
    int s0 = st[0];
    #pragma unroll
    for (int q = 0; q < 16; ++q){
        int s1 = st[q + 1];
        float a = 0.f;
        for (int j = s0; j < s1; ++j){
            int p = pl[j];
            a += h2f(rb[((size_t)p << 8) + t]);
        }
        acc[q] = a;
        s0 = s1;
    }
    unsigned short* go = grid + ((size_t)((b << 8) + t))*HWc + cell0;
    #pragma unroll
    for (int q = 0; q < 16; q += 8){
        ushort8v u;
        #pragma unroll
        for (int j = 0; j < 8; ++j) u[j] = f2h(acc[q+j]);
        *(ushort8v*)(go + q) = u;
    }
}

// ---------------- K2: fused dwconv3 -> relu -> dwconv3 (+skip) + BN partial sums (fp16 IO) ------
__global__ __launch_bounds__(256) void k2_conv(const unsigned short* __restrict__ grid,
                                               const unsigned short* __restrict__ skip,
                                               unsigned short* __restrict__ plane,
                                               const float* __restrict__ w1, const float* __restrict__ b1,
                                               const float* __restrict__ w2, const float* __restrict__ b2,
                                               const float* __restrict__ asc,
                                               float* __restrict__ bnS, float* __restrict__ bnQ,
                                               int useskip){
    __shared__ float it[36*132];
    __shared__ float mid[34*132];
    int tid = threadIdx.x;
    int bi = blockIdx.x;
    int rt = bi & 3;
    int bc = bi >> 2;              // b*256+c
    int c = bc & 255;
    int r0 = rt << 5;
    const unsigned short* src = grid + (size_t)bc*HWc;
    const unsigned short* sk  = skip + (size_t)bc*HWc;
    for (int i = tid; i < 36*132; i += 256){
        int r = i / 132, cc = i - r*132;
        int gy = r0 - 2 + r, gx = cc - 2;
        float v = 0.f;
        if ((unsigned)gy < 128u && (unsigned)gx < 128u){
            int o = (gy << 7) + gx;
            v = h2f(src[o]);
            if (useskip) v += h2f(sk[o]);
        }
        it[i] = v;
    }
    float a1[9], a2[9];
    #pragma unroll
    for (int j = 0; j < 9; ++j){ a1[j] = w1[c*9+j]; a2[j] = w2[c*9+j]; }
    float bb1 = b1[c], bb2 = b2[c], sc = asc[c];
    __syncthreads();
    for (int i = tid; i < 34*130; i += 256){
        int r = i / 130, cc = i - r*130;
        int y = r0 - 1 + r, x = cc - 1;
        float v = 0.f;
        if ((unsigned)y < 128u && (unsigned)x < 128u){
            float s = 0.f;
            #pragma unroll
            for (int j = 0; j < 9; ++j) s += a1[j] * it[(r + j/3)*132 + cc + (j%3)];
            v = fmaxf(s + bb1, 0.f);
        }
        mid[r*132 + cc] = v;
    }
    __syncthreads();
    float ps = 0.f, pq = 0.f;
    unsigned short* dst = plane + (size_t)bc*HWc;
    for (int i = tid; i < 32*128; i += 256){
        int yy = i >> 7, x = i & 127;
        float s = 0.f;
        #pragma unroll
        for (int j = 0; j < 9; ++j) s += a2[j] * mid[(yy + j/3)*132 + x + (j%3)];
        float v = s + bb2;
        dst[((r0 + yy) << 7) + x] = f2h(v);
        float t = v * sc;
        ps += t; pq += t*t;
    }
    __syncthreads();
    it[tid] = ps; it[256 + tid] = pq;
    __syncthreads();
    for (int s2 = 128; s2 > 0; s2 >>= 1){
        if (tid < s2){ it[tid] += it[tid+s2]; it[256+tid] += it[256+tid+s2]; }
        __syncthreads();
    }
    if (tid == 0){
        atomicAdd(&bnS[c], it[0]);
        atomicAdd(&bnQ[c], it[256]);
    }
}

// ---------------- K2b: fold BN into per-channel affine P,Q ----------------
__global__ __launch_bounds__(256) void k2b_bn(const float* __restrict__ bnS, const float* __restrict__ bnQ,
                                              const float* __restrict__ asc,
                                              const float* __restrict__ bng, const float* __restrict__ bnb,
                                              float* __restrict__ P, float* __restrict__ Q){
    int c = threadIdx.x;
    float mean = bnS[c] * (1.f/32768.f);
    float var  = bnQ[c] * (1.f/32768.f) - mean*mean;
    float inv  = rsqrtf(fmaxf(var, 0.f) + 1e-5f) * bng[c];
    P[c] = asc[c] * inv;
    Q[c] = bnb[c] - mean * inv;
}

// ---------------- K3t: sigmoid gate + transpose plane -> attp fp16 [b][hw][c] ----------------
__global__ __launch_bounds__(256) void k3t_att_t(const unsigned short* __restrict__ plane,
                                                 const float* __restrict__ P, const float* __restrict__ Q,
                                                 unsigned short* __restrict__ attp){
    __shared__ float t[32*33];
    int tid = threadIdx.x;
    int tx = tid & 31, ty = tid >> 5;
    int bi = blockIdx.x;
    int ht = bi & 511;
    int ct = (bi >> 9) & 7;
    int b  = bi >> 12;
    int c0 = ct << 5, h0 = ht << 5;
    for (int r = ty; r < 32; r += 8){
        int c = c0 + r;
        float v = h2f(plane[(((size_t)b << 8) + c)*HWc + h0 + tx]);
        float s = 1.f / (1.f + __expf(-(P[c]*v + Q[c])));
        t[r*33 + tx] = s * v;
    }
    __syncthreads();
    for (int r = ty; r < 32; r += 8){
        attp[(((size_t)b << 14) + h0 + r)*Cc + c0 + tx] = f2h(t[tx*33 + r]);
    }
}

// ---------------- K4: gather + cmix LN + MFMA mm1(relu) + mm2 + residual + next-depth LN ----------
// Single LDS arena [point][channel] stride 264; thread (p,cg) owns point p, channels c0..c0+31.
__global__ __launch_bounds__(256) void k4_cmix(const float* __restrict__ tsrc,
                                               const unsigned short* __restrict__ attp,  // fp16 [b][hw][c]
                                               const int* __restrict__ ci,
                                               const unsigned short* __restrict__ W1,
                                               const unsigned short* __restrict__ W2,
                                               const float* __restrict__ lng, const float* __restrict__ lnb,
                                               const float* __restrict__ b1, const float* __restrict__ b2,
                                               const float* __restrict__ csc,
                                               const float* __restrict__ lng2, const float* __restrict__ lnb2,
                                               const float* __restrict__ wptb,
                                               float* __restrict__ out,
                                               unsigned short* __restrict__ rbufn,      // fp16 [b][n][c]
                                               int g, int g2, int donext){
    __shared__ __align__(16) unsigned short hs[32*264];    // 16.9 KB: h -> h1 -> h2
    __shared__ float reds[256], redq[256];
    __shared__ float m_s[32], r_s[32];
    __shared__ int cell_s[32];
    __shared__ float lng_s[Cc], lnb_s[Cc], b1_s[Cc], b2s_s[Cc], cs_s[Cc], g2g_s[Cc], g2b_s[Cc];

    int tid = threadIdx.x;
    int bi = blockIdx.x;
    int b = bi >> 10;              // 1024 blocks per batch, 32 points each
    int p0 = (bi & 1023) << 5;

    lng_s[tid] = lng[tid];
    lnb_s[tid] = lnb[tid];
    b1_s[tid]  = b1[tid];
    float cv = csc[tid];
    cs_s[tid]  = cv;
    b2s_s[tid] = b2[tid] * cv;
    g2g_s[tid] = lng2[tid];
    g2b_s[tid] = lnb2[tid];
    if (tid < 32){
        int cc = ci[(b*3 + g)*Nn + p0 + tid];
        cell_s[tid] = min(max(cc, 0), HWc-1);
    }
    __syncthreads();

    int p  = tid & 31;
    int cg = tid >> 5;
    int c0 = cg << 5;

    // ---- direct register gather: tokens (strided fp32) + attp row chunk (4x16B) ----
    const float* tb = tsrc + ((size_t)b << 8)*Nn + p0 + p;
    const unsigned short* ar = attp + ((size_t)((b << 14) + cell_s[p]))*Cc + c0;
    ushort8v rr[4];
    #pragma unroll
    for (int j = 0; j < 4; ++j) rr[j] = *(const ushort8v*)(ar + 8*j);

    float vreg[32];
    float sum = 0.f, sq = 0.f;
    #pragma unroll
    for (int k = 0; k < 32; ++k){
        float v = tb[(size_t)(c0 + k) << 15] + h2f(rr[k >> 3][k & 7]);
        vreg[k] = v; sum += v; sq += v*v;
    }
    reds[tid] = sum; redq[tid] = sq;
    __syncthreads();
    if (tid < 32){
        float s = 0.f, q = 0.f;
        #pragma unroll
        for (int j = 0; j < 8; ++j){ s += reds[j*32 + tid]; q += redq[j*32 + tid]; }
        float m = s * (1.f/256.f);
        float var = q * (1.f/256.f) - m*m;
        m_s[tid] = m;
        r_s[tid] = rsqrtf(fmaxf(var, 0.f) + 1e-5f);
    }
    __syncthreads();
    float mp = m_s[p], rp = r_s[p];
    unsigned short* hrow = &hs[p*264 + c0];
    #pragma unroll
    for (int j = 0; j < 4; ++j){
        ushort8v u;
        #pragma unroll
        for (int e = 0; e < 8; ++e){
            int k = j*8 + e, c = c0 + k;
            u[e] = f2b((vreg[k] - mp)*rp*lng_s[c] + lnb_s[c]);
        }
        *(ushort8v*)(hrow + 8*j) = u;
    }
    __syncthreads();

    int lane = tid & 63;
    int w = tid >> 6;
    int l15 = lane & 15;
    int q4 = lane >> 4;
    floatx4 acc[4][2];
    #pragma unroll
    for (int mi = 0; mi < 4; ++mi)
        #pragma unroll
        for (int ni = 0; ni < 2; ++ni)
            acc[mi][ni] = (floatx4){0.f, 0.f, 0.f, 0.f};

    // mm1: h1 = relu(W1 @ h + b1)
    #pragma unroll
    for (int kk = 0; kk < 8; ++kk){
        int k0 = kk*32 + q4*8;
        bf16x8 bfr[2];
        #pragma unroll
        for (int ni = 0; ni < 2; ++ni)
            bfr[ni] = *(const bf16x8*)&hs[(ni*16 + l15)*264 + k0];
        #pragma unroll
        for (int mi = 0; mi < 4; ++mi){
            bf16x8 af = *(const bf16x8*)&W1[(size_t)(w*64 + mi*16 + l15)*Cc + k0];
            #pragma unroll
            for (int ni = 0; ni < 2; ++ni)
                acc[mi][ni] = __builtin_amdgcn_mfma_f32_16x16x32_bf16(af, bfr[ni], acc[mi][ni], 0, 0, 0);
        }
    }
    __syncthreads();   // all h reads done
    #pragma unroll
    for (int mi = 0; mi < 4; ++mi)
        #pragma unroll
        for (int ni = 0; ni < 2; ++ni){
            int m0 = w*64 + mi*16 + q4*4;
            int nn = ni*16 + l15;
            ushort4v u;
            #pragma unroll
            for (int r = 0; r < 4; ++r)
                u[r] = f2b(fmaxf(acc[mi][ni][r] + b1_s[m0 + r], 0.f));
            *(ushort4v*)&hs[nn*264 + m0] = u;   // h1 [point][channel]
        }
    __syncthreads();

    // mm2: h2 = (W2 @ h1)*cs + b2*cs
    #pragma unroll
    for (int mi = 0; mi < 4; ++mi)
        #pragma unroll
        for (int ni = 0; ni < 2; ++ni)
            acc[mi][ni] = (floatx4){0.f, 0.f, 0.f, 0.f};
    #pragma unroll
    for (int kk = 0; kk < 8; ++kk){
        int k0 = kk*32 + q4*8;
        bf16x8 bfr[2];
        #pragma unroll
        for (int ni = 0; ni < 2; ++ni)
            bfr[ni] = *(const bf16x8*)&hs[(ni*16 + l15)*264 + k0];
        #pragma unroll
        for (int mi = 0; mi < 4; ++mi){
            bf16x8 af = *(const bf16x8*)&W2[(size_t)(w*64 + mi*16 + l15)*Cc + k0];
            #pragma unroll
            for (int ni = 0; ni < 2; ++ni)
                acc[mi][ni] = __builtin_amdgcn_mfma_f32_16x16x32_bf16(af, bfr[ni], acc[mi][ni], 0, 0, 0);
        }
    }
    __syncthreads();   // all h1 reads done
    #pragma unroll
    for (int mi = 0; mi < 4; ++mi)
        #pragma unroll
        for (int ni = 0; ni < 2; ++ni){
            int m0 = w*64 + mi*16 + q4*4;
            int nn = ni*16 + l15;
            ushort4v u;
            #pragma unroll
            for (int r = 0; r < 4; ++r)
                u[r] = f2b(acc[mi][ni][r]*cs_s[m0 + r] + b2s_s[m0 + r]);
            *(ushort4v*)&hs[nn*264 + m0] = u;   // h2 [point][channel]
        }
    __syncthreads();

    // ---- epilogue: tokens += h2; out write; optional next-depth LN*wpt -> rbuf (direct) ----
    float sum2 = 0.f, sq2 = 0.f;
    float* ob = out + ((size_t)b << 8)*Nn + p0 + p;
    #pragma unroll
    for (int j = 0; j < 4; ++j){
        ushort8v u = *(const ushort8v*)(hrow + 8*j);
        #pragma unroll
        for (int e = 0; e < 8; ++e){
            int k = j*8 + e, c = c0 + k;
            float v = vreg[k] + b2f(u[e]);
            vreg[k] = v;
            ob[(size_t)c << 15] = v;
            sum2 += v; sq2 += v*v;
        }
    }
    if (donext){
        reds[tid] = sum2; redq[tid] = sq2;
        __syncthreads();
        if (tid < 32){
            float s = 0.f, q = 0.f;
            #pragma unroll
            for (int j = 0; j < 8; ++j){ s += reds[j*32 + tid]; q += redq[j*32 + tid]; }
            float m = s * (1.f/256.f);
            float var = q * (1.f/256.f) - m*m;
            m_s[tid] = m;
            r_s[tid] = rsqrtf(fmaxf(var, 0.f) + 1e-5f);
        }
        __syncthreads();
        float m2 = m_s[p], rr2 = r_s[p];
        float wv2 = wptb[(b*3 + g2)*Nn + p0 + p];
        unsigned short* rb = rbufn + ((size_t)((b << 15) + p0 + p))*Cc + c0;
        #pragma unroll
        for (int j = 0; j < 4; ++j){
            ushort8v u;
            #pragma unroll
            for (int e = 0; e < 8; ++e){
                int k = j*8 + e, c = c0 + k;
                u[e] = f2h(((vreg[k] - m2)*rr2*g2g_s[c] + g2b_s[c]) * wv2);
            }
            *(ushort8v*)(rb + 8*j) = u;
        }
    }
}

extern "C" void kernel_launch(void* const* d_in, const int* in_sizes, int n_in,
                              void* d_out, int out_size, void* d_ws, size_t ws_size,
                              hipStream_t stream){
    (void)in_sizes; (void)n_in; (void)out_size; (void)ws_size;
    const float* tokens  = (const float*)d_in[0];
    const int*   cellind = (const int*)d_in[1];
    const float* occ     = (const float*)d_in[2];
    const float* smix_g  = (const float*)d_in[3];
    const float* smix_b  = (const float*)d_in[4];
    const float* ffn_w1  = (const float*)d_in[5];
    const float* ffn_b1  = (const float*)d_in[6];
    const float* ffn_w2  = (const float*)d_in[7];
    const float* ffn_b2  = (const float*)d_in[8];
    const float* att_sc  = (const float*)d_in[9];
    const float* bn_g    = (const float*)d_in[10];
    const float* bn_b    = (const float*)d_in[11];
    const float* cm_g    = (const float*)d_in[12];
    const float* cm_b    = (const float*)d_in[13];
    const float* cw1     = (const float*)d_in[14];
    const float* cb1     = (const float*)d_in[15];
    const float* cw2     = (const float*)d_in[16];
    const float* cb2     = (const float*)d_in[17];
    const float* cscale  = (const float*)d_in[18];
    float* out = (float*)d_out;
    char* w = (char*)d_ws;

    const size_t HGRID_BYTES = (size_t)Bb*Cc*HWc*2;          // 16777216
    unsigned short* grid_h  = (unsigned short*)(w);
    unsigned short* attp_h  = grid_h;                        // alias: grid dead after k2
    unsigned short* planeA  = (unsigned short*)(w + HGRID_BYTES);
    unsigned short* planeB  = (unsigned short*)(w + 2*HGRID_BYTES);
    unsigned short* rbuf    = (unsigned short*)(w + 3*HGRID_BYTES);  // [b][n][c] fp16, 33.5 MB
    size_t o = 3*HGRID_BYTES + (size_t)Bb*Nn*Cc*2;
    float* fcounts = (float*)(w + o); o += (size_t)Bb*3*HWc*4;
    int*   icounts = (int*)(w + o);   o += (size_t)Bb*3*HWc*4;
    float* wptb   = (float*)(w + o); o += (size_t)Bb*3*Nn*4;
    float* bnS    = (float*)(w + o);
    float* bnQ    = bnS + 256;
    float* Pb     = bnS + 512;
    float* Qb     = bnS + 768;
    o += 4096;
    unsigned short* W1b = (unsigned short*)(w + o);
    unsigned short* W2b = W1b + 4*Cc*Cc;
    o += (size_t)2*4*Cc*Cc*2;
    int* startsb  = (int*)(w + o); o += (size_t)Bb*3*(HWc+1)*4;
    int* cursors  = (int*)(w + o); o += (size_t)Bb*3*HWc*4;
    int* plistb   = (int*)(w + o); o += (size_t)Bb*3*Nn*4;

    // ---- setup (once per launch) ----
    hipMemsetAsync(fcounts, 0, (size_t)2*Bb*3*HWc*4, stream);
    k_count<<<(Bb*3*Nn)/256, 256, 0, stream>>>(cellind, occ, fcounts, icounts);
    k_wpt<<<(Bb*3*Nn)/256, 256, 0, stream>>>(cellind, occ, fcounts, wptb);
    k_scan<<<Bb*3, 256, 0, stream>>>(icounts, startsb, cursors);
    k_fill<<<(Bb*3*Nn)/256, 256, 0, stream>>>(cellind, cursors, plistb);
    k_wcvt<<<(4*Cc*Cc)/256, 256, 0, stream>>>(cw1, cw2, W1b, W2b);

    // depth-0 rbuf from input tokens
    k1a_ln<<<Bb*(Nn/256), 256, 0, stream>>>(tokens, wptb, smix_g, smix_b, rbuf, 0);

    for (int d = 0; d < 4; ++d){
        int g = d % 3;
        int g2 = (d + 1) % 3;
        int donext = (d < 3) ? 1 : 0;
        int useskip = (d == 3) ? 1 : 0;
        unsigned short* plane = (d == 0) ? planeA : planeB;
        const float* tsrc = (d == 0) ? tokens : out;
        int dn = (d + 1 < 4) ? d + 1 : d;   // next depth params (unused when donext=0)

        hipMemsetAsync(bnS, 0, 2048, stream);

        k1b_gather<<<Bb*(HWc/16), 256, 0, stream>>>(rbuf, startsb, plistb, grid_h, g);
        k2_conv<<<Bb*Cc*4, 256, 0, stream>>>(grid_h, planeA, plane,
                                             ffn_w1 + d*Cc*9, ffn_b1 + d*Cc,
                                             ffn_w2 + d*Cc*9, ffn_b2 + d*Cc,
                                             att_sc + d*Cc, bnS, bnQ, useskip);
        k2b_bn<<<1, 256, 0, stream>>>(bnS, bnQ, att_sc + d*Cc, bn_g + d*Cc, bn_b + d*Cc, Pb, Qb);
        k3t_att_t<<<Bb*8*512, 256, 0, stream>>>(plane, Pb, Qb, attp_h);
        k4_cmix<<<Bb*(Nn/32), 256, 0, stream>>>(tsrc, attp_h, cellind,
                                                W1b + (size_t)d*Cc*Cc, W2b + (size_t)d*Cc*Cc,
                                                cm_g + d*Cc, cm_b + d*Cc,
                                                cb1 + d*Cc, cb2 + d*Cc, cscale + d*Cc,
                                                smix_g + dn*Cc, smix_b + dn*Cc, wptb,
                                                out, rbuf, g, g2, donext);
    }
}